// Round 14
// baseline (455.127 us; speedup 1.0000x reference)
//
#include <hip/hip_runtime.h>

#define CC 128
#define ECAP 512

typedef __attribute__((ext_vector_type(8))) short bf16x8;
typedef __attribute__((ext_vector_type(4))) float f32x4;
#define MFMA16(a, b, c) __builtin_amdgcn_mfma_f32_16x16x32_bf16(a, b, c, 0, 0, 0)

__device__ __forceinline__ float enc_nan(float v) {
    if (v != v) return 0.f;
    if (v > 3.0e38f) return 1.f;
    if (v < -3.0e38f) return -1.f;
    return v;
}

__device__ __forceinline__ ushort f2bf(float x) {
    unsigned u = __builtin_bit_cast(unsigned, x);
    u += 0x7fff + ((u >> 16) & 1);
    return (ushort)(u >> 16);
}
__device__ __forceinline__ float bf2f(ushort h) {
    return __builtin_bit_cast(float, ((unsigned)h) << 16);
}

__device__ __forceinline__ int swz128(int row, int k) { return (row * 128 + k) ^ ((row & 7) << 3); }

// ---------- fused setup: init(a,b) | weight-cvt | edge histogram ----------
__global__ __launch_bounds__(256)
void k_setup(const float* __restrict__ xa_in, ushort* __restrict__ xa,
             float2* __restrict__ stat_a, int NA,
             const float* __restrict__ xb_in, ushort* __restrict__ xb,
             float2* __restrict__ stat_b, int NB,
             const float* __restrict__ pw1, const float* __restrict__ pw2,
             const float* __restrict__ uw,
             ushort* __restrict__ w1t, ushort* __restrict__ w2t, ushort* __restrict__ uwt,
             const int* __restrict__ dst_b, int Eab, int* __restrict__ cnt_b,
             const int* __restrict__ dst_a, int Eba, int* __restrict__ cnt_a,
             int Ginit, int Gwcvt)
{
    const int b = blockIdx.x;
    const int tid = threadIdx.x;
    if (b < Ginit) {
        int row = b * 8 + (tid >> 5);
        int s = tid & 31;
        const float* xin; ushort* xo; float2* st;
        if (row < NA) { xin = xa_in; xo = xa; st = stat_a; }
        else {
            row -= NA;
            if (row >= NB) return;
            xin = xb_in; xo = xb; st = stat_b;
        }
        float4 v = *reinterpret_cast<const float4*>(xin + (size_t)row * CC + s * 4);
        ushort h0 = f2bf(enc_nan(v.x)), h1 = f2bf(enc_nan(v.y));
        ushort h2 = f2bf(enc_nan(v.z)), h3 = f2bf(enc_nan(v.w));
        *reinterpret_cast<ushort4*>(xo + (size_t)row * CC + s * 4) = make_ushort4(h0, h1, h2, h3);
        float r0 = bf2f(h0), r1 = bf2f(h1), r2 = bf2f(h2), r3 = bf2f(h3);
        float sm = (r0 + r1) + (r2 + r3);
        float sq = fmaf(r0, r0, fmaf(r1, r1, fmaf(r2, r2, r3 * r3)));
        #pragma unroll
        for (int m = 1; m < 32; m <<= 1) { sm += __shfl_xor(sm, m); sq += __shfl_xor(sq, m); }
        if (s == 0) st[row] = make_float2(sm, sq);
    } else if (b < Ginit + Gwcvt) {
        int i = (b - Ginit) * 256 + tid;   // 4 types x 65536
        int t = i >> 16;
        int r = i & 65535;
        if (r < 16384) {
            int k = r >> 7, c = r & 127;
            w1t[(size_t)t * 16384 + c * 128 + k] = f2bf(pw1[(size_t)t * 16384 + k * 128 + c]);
        } else if (r < 32768) {
            int rr = r - 16384;
            int k = rr >> 7, c = rr & 127;
            w2t[(size_t)t * 16384 + c * 128 + k] = f2bf(pw2[(size_t)t * 16384 + k * 128 + c]);
        } else {
            int rr = r - 32768;
            int k = rr >> 7, c = rr & 127;
            uwt[(size_t)t * 32768 + c * 256 + k] = f2bf(uw[(size_t)t * 32768 + k * 128 + c]);
        }
    } else {
        int i = (b - Ginit - Gwcvt) * 256 + tid;
        if (i < Eab) atomicAdd(&cnt_b[dst_b[i]], 1);
        else if (i - Eab < Eba) atomicAdd(&cnt_a[dst_a[i - Eab]], 1);
    }
}

// ---------- degree-sort: 64-bucket histogram | scan | perm/rank scatter ----------
__global__ __launch_bounds__(256)
void k_dhist(const int* __restrict__ cnt_b, int NB, const int* __restrict__ cnt_a, int NA,
             int* __restrict__ dh)
{
    int i = blockIdx.x * 256 + threadIdx.x;
    if (i < NB) {
        int d = cnt_b[i]; if (d > 63) d = 63;
        atomicAdd(&dh[d], 1);
    } else if (i - NB < NA) {
        int d = cnt_a[i - NB]; if (d > 63) d = 63;
        atomicAdd(&dh[64 + d], 1);
    }
}

__global__ __launch_bounds__(128)
void k_dscan(const int* __restrict__ dh, int* __restrict__ dbase)
{
    const int tid = threadIdx.x, lane = tid & 63;
    int v = dh[tid];
    int incl = v;
    #pragma unroll
    for (int d = 1; d < 64; d <<= 1) {
        int t = __shfl_up(incl, d);
        if (lane >= d) incl += t;
    }
    dbase[tid] = incl - v;   // exclusive, per 64-entry segment
}

__global__ __launch_bounds__(256)
void k_dperm(const int* __restrict__ cnt_b, int NB, int* __restrict__ dbase,
             int* __restrict__ perm_b, int* __restrict__ rank_b, int* __restrict__ cnt_sb,
             const int* __restrict__ cnt_a, int NA,
             int* __restrict__ perm_a, int* __restrict__ rank_a, int* __restrict__ cnt_sa)
{
    int i = blockIdx.x * 256 + threadIdx.x;
    if (i < NB) {
        int deg = cnt_b[i];
        int d = deg > 63 ? 63 : deg;
        int r = atomicAdd(&dbase[d], 1);
        perm_b[r] = i; rank_b[i] = r; cnt_sb[r] = deg;
    } else if (i - NB < NA) {
        int j = i - NB;
        int deg = cnt_a[j];
        int d = deg > 63 ? 63 : deg;
        int r = atomicAdd(&dbase[64 + d], 1);
        perm_a[r] = j; rank_a[j] = r; cnt_sa[r] = deg;
    }
}

// ---------- parallel scan, phase A ----------
__global__ __launch_bounds__(256)
void k_scanA(const int* __restrict__ cnt0, int* __restrict__ rowp0, int* __restrict__ part0,
             int n0, int Gb0,
             const int* __restrict__ cnt1, int* __restrict__ rowp1, int* __restrict__ part1, int n1)
{
    const int b = blockIdx.x;
    const bool sel = b < Gb0;
    const int* cnt = sel ? cnt0 : cnt1;
    int* rowp      = sel ? rowp0 : rowp1;
    int* part      = sel ? part0 : part1;
    const int n    = sel ? n0 : n1;
    const int bb   = sel ? b : b - Gb0;

    __shared__ int wsum[4];
    const int tid = threadIdx.x, lane = tid & 63, wid = tid >> 6;
    const int i = bb * 256 + tid;
    int v = (i < n) ? cnt[i] : 0;
    int incl = v;
    #pragma unroll
    for (int d = 1; d < 64; d <<= 1) {
        int t = __shfl_up(incl, d);
        if (lane >= d) incl += t;
    }
    if (lane == 63) wsum[wid] = incl;
    __syncthreads();
    int base = 0;
    #pragma unroll
    for (int j = 0; j < 4; ++j) if (j < wid) base += wsum[j];
    int excl = base + incl - v;
    if (i < n) rowp[i] = excl;
    if (tid == 255) part[bb] = excl + v;
}

// ---------- parallel scan, phase B ----------
__global__ __launch_bounds__(256)
void k_scanB(int* __restrict__ rowp0, const int* __restrict__ part0, int* __restrict__ off0,
             int n0, int Gb0,
             int* __restrict__ rowp1, const int* __restrict__ part1, int* __restrict__ off1, int n1)
{
    const int b = blockIdx.x;
    const bool sel = b < Gb0;
    int* rowp       = sel ? rowp0 : rowp1;
    const int* part = sel ? part0 : part1;
    int* off        = sel ? off0 : off1;
    const int n     = sel ? n0 : n1;
    const int bb    = sel ? b : b - Gb0;
    const int Gl    = sel ? Gb0 : (int)gridDim.x - Gb0;

    __shared__ int base_s;
    const int tid = threadIdx.x;
    if (tid < 64) {
        int s = 0;
        for (int j = tid; j < bb; j += 64) s += part[j];
        #pragma unroll
        for (int m = 1; m < 64; m <<= 1) s += __shfl_xor(s, m);
        if (tid == 0) base_s = s;
    }
    __syncthreads();
    const int base = base_s;
    const int i = bb * 256 + tid;
    if (i < n) {
        int r = rowp[i] + base;
        rowp[i] = r;
        off[i] = r;
    }
    if (bb == Gl - 1 && tid == 0) rowp[n] = base + part[bb];
}

// ---------- edge scatter into sorted CSR (via rank) ----------
__global__ __launch_bounds__(256)
void k_scatter_dual(const int* __restrict__ src_b, const int* __restrict__ dst_b, int Eab,
                    const int* __restrict__ rank_b, int* __restrict__ off_b, int* __restrict__ srcs_ab,
                    const int* __restrict__ src_a, const int* __restrict__ dst_a, int Eba,
                    const int* __restrict__ rank_a, int* __restrict__ off_a, int* __restrict__ srcs_ba)
{
    int i = blockIdx.x * 256 + threadIdx.x;
    if (i < Eab) {
        int p = atomicAdd(&off_b[rank_b[dst_b[i]]], 1);
        srcs_ab[p] = src_b[i];
    } else if (i - Eab < Eba) {
        int j = i - Eab;
        int p = atomicAdd(&off_a[rank_a[dst_a[j]]], 1);
        srcs_ba[p] = src_a[j];
    }
}

// ---------- fully fused conv: 32-node (degree-sorted) tile, 8 waves ----------
__device__ __forceinline__ void layer_body(
    char* smem,
    const ushort* __restrict__ xdst, const ushort* __restrict__ xsrc,
    const float2* __restrict__ stat_src, const int* __restrict__ perm,
    const int* __restrict__ rowp, const int* __restrict__ srcs,
    const ushort* __restrict__ w1t, const float* __restrict__ b1,
    const ushort* __restrict__ w2t, const float* __restrict__ b2,
    const float* __restrict__ mg, const float* __restrict__ mbt,
    const ushort* __restrict__ uwt, const float* __restrict__ ub,
    const float* __restrict__ ng, const float* __restrict__ nb,
    ushort* __restrict__ xout, float2* __restrict__ statOut, int N, int blk,
    const float* __restrict__ hw, const float* __restrict__ hb,
    float* __restrict__ hout, int headS)
{
    ushort* As = (ushort*)smem;              // 32x128 bf16, swizzled (x_dst, sorted order)
    ushort* Hs = (ushort*)(smem + 8192);     // 32x128 bf16, swizzled (relu(h), then agg)
    ushort* P  = (ushort*)(smem + 16384);    // 32x128 bf16, linear (pred)
    float (*os)[CC + 4] = (float(*)[CC + 4])(smem + 8192);  // overlays Hs+P after update GEMM
    int* sL   = (int*)(smem + 25088);        // block srcs slice (ECAP ints)
    int* shrp = (int*)(smem + 25088 + ECAP * 4);  // 33-entry rowp slice

    const int tid = threadIdx.x;
    const int base = blk * 32;
    const int w = tid >> 6, l = tid & 63;
    const int lr = l & 15, lg = l >> 4;

    if (tid < 33) {
        int nn = base + tid;
        shrp[tid] = rowp[nn < N ? nn : N];
    }
    {   // stage x_dst (permuted rows) -> As (swizzled): one bf16x8 per thread
        int row = tid >> 4, k0 = (tid & 15) << 3;
        int pnode = base + row;
        bf16x8 v0 = {};
        if (pnode < N) {
            int anode = perm[pnode];
            v0 = *reinterpret_cast<const bf16x8*>(xdst + (size_t)anode * CC + k0);
        }
        *reinterpret_cast<bf16x8*>(&As[swz128(row, k0)]) = v0;
    }
    // stage the block's srcs slice (wave-uniform bounds; one int per thread)
    const int jb0 = rowp[base];
    {
        int top = base + 32; if (top > N) top = N;
        const int je0 = rowp[top];
        int ec = je0 - jb0; if (ec > ECAP) ec = ECAP;
        if (tid < ec) sL[tid] = srcs[jb0 + tid];
    }
    __syncthreads();

    // pred GEMM1: Hs = relu(As @ w1 + b1); wave w owns cols [w*16, w*16+16)
    {
        f32x4 acc[2] = {};
        for (int kb = 0; kb < 4; ++kb) {
            int k = kb * 32 + lg * 8;
            bf16x8 a0 = *reinterpret_cast<const bf16x8*>(&As[swz128(lr, k)]);
            bf16x8 a1 = *reinterpret_cast<const bf16x8*>(&As[swz128(lr + 16, k)]);
            bf16x8 b0 = *reinterpret_cast<const bf16x8*>(&w1t[(size_t)(w * 16 + lr) * 128 + k]);
            acc[0] = MFMA16(a0, b0, acc[0]);
            acc[1] = MFMA16(a1, b0, acc[1]);
        }
        float bc = b1[w * 16 + lr];
        int col = w * 16 + lr;
        #pragma unroll
        for (int mi = 0; mi < 2; ++mi)
            #pragma unroll
            for (int j = 0; j < 4; ++j) {
                int row = mi * 16 + lg * 4 + j;
                Hs[swz128(row, col)] = f2bf(fmaxf(acc[mi][j] + bc, 0.f));
            }
    }
    __syncthreads();

    // pred GEMM2: P = Hs @ w2 + b2  (linear layout)
    {
        f32x4 acc[2] = {};
        for (int kb = 0; kb < 4; ++kb) {
            int k = kb * 32 + lg * 8;
            bf16x8 a0 = *reinterpret_cast<const bf16x8*>(&Hs[swz128(lr, k)]);
            bf16x8 a1 = *reinterpret_cast<const bf16x8*>(&Hs[swz128(lr + 16, k)]);
            bf16x8 b0 = *reinterpret_cast<const bf16x8*>(&w2t[(size_t)(w * 16 + lr) * 128 + k]);
            acc[0] = MFMA16(a0, b0, acc[0]);
            acc[1] = MFMA16(a1, b0, acc[1]);
        }
        float bc = b2[w * 16 + lr];
        int col = w * 16 + lr;
        #pragma unroll
        for (int mi = 0; mi < 2; ++mi)
            #pragma unroll
            for (int j = 0; j < 4; ++j) {
                int row = mi * 16 + lg * 4 + j;
                P[row * CC + col] = f2bf(acc[mi][j] + bc);
            }
    }
    __syncthreads();

    // agg phase: wave w owns sorted nodes w*4..w*4+3; quarter-wave = 4 edges in flight
    {
        const int quarter = l >> 4;
        const int c = (l & 15) * 8;
        const float4 g0 = *reinterpret_cast<const float4*>(mg + c);
        const float4 g1 = *reinterpret_cast<const float4*>(mg + c + 4);
        const float4 e0 = *reinterpret_cast<const float4*>(mbt + c);
        const float4 e1 = *reinterpret_cast<const float4*>(mbt + c + 4);
        const float gv[8] = { g0.x, g0.y, g0.z, g0.w, g1.x, g1.y, g1.z, g1.w };
        const float bv[8] = { e0.x, e0.y, e0.z, e0.w, e1.x, e1.y, e1.z, e1.w };
        for (int i = 0; i < 4; ++i) {
            const int nl_ = w * 4 + i;
            const int d = base + nl_;
            if (d >= N) break;
            bf16x8 prb = *reinterpret_cast<const bf16x8*>(&P[nl_ * CC + c]);
            float pr[8];
            #pragma unroll
            for (int q = 0; q < 8; ++q) pr[q] = bf2f((ushort)prb[q]);
            float sp = 0.f, qp = 0.f;
            #pragma unroll
            for (int q = 0; q < 8; ++q) { sp += pr[q]; qp = fmaf(pr[q], pr[q], qp); }
            #pragma unroll
            for (int m = 1; m < 16; m <<= 1) { sp += __shfl_xor(sp, m); qp += __shfl_xor(qp, m); }
            const int jb = shrp[nl_], je = shrp[nl_ + 1];
            const int deg = je - jb;
            float a[8] = {};
            float rsum = 0.f, cmsum = 0.f;
            for (int j = jb + quarter; j < je; j += 4) {
                const int le = j - jb0;
                const int sidx = (le < ECAP) ? sL[le] : srcs[j];
                bf16x8 xb_ = *reinterpret_cast<const bf16x8*>(xsrc + (size_t)sidx * CC + c);
                const float2 st = stat_src[sidx];
                float xj[8];
                #pragma unroll
                for (int q = 0; q < 8; ++q) xj[q] = bf2f((ushort)xb_[q]);
                float dA = 0.f, dB = 0.f;
                #pragma unroll
                for (int q = 0; q < 4; ++q) dA = fmaf(xj[q], pr[q], dA);
                #pragma unroll
                for (int q = 4; q < 8; ++q) dB = fmaf(xj[q], pr[q], dB);
                float dot = dA + dB;
                #pragma unroll
                for (int m = 1; m < 16; m <<= 1) dot += __shfl_xor(dot, m);
                const float mean = (st.x - sp) * (1.f / 128.f);
                const float var = fmaf(-2.f, dot, st.y + qp) * (1.f / 128.f) - mean * mean;
                const float r = rsqrtf(var + 1e-5f);
                rsum += r;
                cmsum = fmaf(mean, r, cmsum);
                #pragma unroll
                for (int q = 0; q < 8; ++q) a[q] = fmaf(xj[q], r, a[q]);
            }
            #pragma unroll
            for (int q = 0; q < 8; ++q) { a[q] += __shfl_xor(a[q], 16); a[q] += __shfl_xor(a[q], 32); }
            rsum += __shfl_xor(rsum, 16);  rsum += __shfl_xor(rsum, 32);
            cmsum += __shfl_xor(cmsum, 16); cmsum += __shfl_xor(cmsum, 32);
            if (quarter == 0) {
                ushort o8[8];
                if (deg > 0) {
                    const float inv = 1.f / (float)deg;
                    #pragma unroll
                    for (int q = 0; q < 8; ++q)
                        o8[q] = f2bf(fmaf((a[q] - pr[q] * rsum - cmsum) * inv, gv[q], bv[q]));
                } else {
                    #pragma unroll
                    for (int q = 0; q < 8; ++q) o8[q] = 0;
                }
                *reinterpret_cast<bf16x8*>(&Hs[swz128(nl_, c)]) = *reinterpret_cast<bf16x8*>(&o8[0]);
            }
        }
    }
    __syncthreads();

    // update GEMM: concat(x=As | agg=Hs) @ uwt + ub, K=256; wave w owns 16 cols
    f32x4 acc[2] = {};
    for (int kb = 0; kb < 8; ++kb) {
        int k = kb * 32 + lg * 8;
        const ushort* Ab = (k < 128) ? As : Hs;
        int kl = k & 127;
        bf16x8 a0 = *reinterpret_cast<const bf16x8*>(&Ab[swz128(lr, kl)]);
        bf16x8 a1 = *reinterpret_cast<const bf16x8*>(&Ab[swz128(lr + 16, kl)]);
        bf16x8 b0 = *reinterpret_cast<const bf16x8*>(&uwt[(size_t)(w * 16 + lr) * 256 + k]);
        acc[0] = MFMA16(a0, b0, acc[0]);
        acc[1] = MFMA16(a1, b0, acc[1]);
    }
    __syncthreads();   // all reads of As/Hs done before os overlays them

    {
        float bc = ub[w * 16 + lr];
        int col = w * 16 + lr;
        #pragma unroll
        for (int mi = 0; mi < 2; ++mi)
            #pragma unroll
            for (int j = 0; j < 4; ++j) {
                int row = mi * 16 + lg * 4 + j;
                os[row][col] = fmaxf(acc[mi][j] + bc, 0.f);
            }
    }
    __syncthreads();

    // node LayerNorm + relu + stats (+head); 16 lanes/node, 8 channels/lane
    const int nl = tid >> 4;
    const int cl = tid & 15;
    float vals[8];
    float sm = 0.f, sq = 0.f;
    #pragma unroll
    for (int t = 0; t < 8; ++t) {
        float u = os[nl][cl + 16 * t];
        vals[t] = u; sm += u; sq = fmaf(u, u, sq);
    }
    #pragma unroll
    for (int m = 1; m < 16; m <<= 1) { sm += __shfl_xor(sm, m); sq += __shfl_xor(sq, m); }
    float mean = sm * (1.f / 128.f);
    float var = sq * (1.f / 128.f) - mean * mean;
    float r = rsqrtf(var + 1e-5f);
    int pnode = base + nl;
    if (pnode < N) {
        const int anode = perm[pnode];
        float so = 0.f, sqo = 0.f, hsum = 0.f;
        bool doHead = (anode < headS);
        #pragma unroll
        for (int t = 0; t < 8; ++t) {
            int cch = cl + 16 * t;
            float o = fmaxf(fmaf((vals[t] - mean) * r, ng[cch], nb[cch]), 0.f);
            ushort ob = f2bf(o);
            xout[(size_t)anode * CC + cch] = ob;
            float orr = bf2f(ob);
            so += orr; sqo = fmaf(orr, orr, sqo);
            if (doHead) hsum = fmaf(o, hw[cch], hsum);
        }
        #pragma unroll
        for (int m = 1; m < 16; m <<= 1) { so += __shfl_xor(so, m); sqo += __shfl_xor(sqo, m); }
        if (doHead) {
            #pragma unroll
            for (int m = 1; m < 16; m <<= 1) hsum += __shfl_xor(hsum, m);
            if (cl == 0) hout[anode] = hsum + hb[0];
        }
        if (cl == 0) statOut[anode] = make_float2(so, sqo);
    }
}

__global__ __launch_bounds__(512)
void k_layer_dual(
    const ushort* __restrict__ xb_c, const ushort* __restrict__ xa_c,
    const float2* __restrict__ stat_a_c, const float2* __restrict__ stat_b_c,
    const int* __restrict__ perm_b, const int* __restrict__ perm_a,
    const int* __restrict__ rowp_b, const int* __restrict__ srcs_ab,
    const int* __restrict__ rowp_a, const int* __restrict__ srcs_ba,
    ushort* __restrict__ xb_n, ushort* __restrict__ xa_n,
    float2* __restrict__ stat_b_n, float2* __restrict__ stat_a_n,
    int NB, int NA, int GB,
    const ushort* __restrict__ w1t0, const float* __restrict__ b10,
    const ushort* __restrict__ w2t0, const float* __restrict__ b20,
    const float* __restrict__ mg0, const float* __restrict__ mb0,
    const ushort* __restrict__ uwt0, const float* __restrict__ ub0,
    const float* __restrict__ ng0, const float* __restrict__ nb0,
    const ushort* __restrict__ w1t1, const float* __restrict__ b11,
    const ushort* __restrict__ w2t1, const float* __restrict__ b21,
    const float* __restrict__ mg1, const float* __restrict__ mb1,
    const ushort* __restrict__ uwt1, const float* __restrict__ ub1,
    const float* __restrict__ ng1, const float* __restrict__ nb1,
    const float* __restrict__ hw, const float* __restrict__ hb,
    float* __restrict__ hout, int headS)
{
    __shared__ __align__(16) char smem[25088 + ECAP * 4 + 144];
    if ((int)blockIdx.x < GB)
        layer_body(smem, xb_c, xa_c, stat_a_c, perm_b, rowp_b, srcs_ab,
                   w1t0, b10, w2t0, b20, mg0, mb0, uwt0, ub0, ng0, nb0,
                   xb_n, stat_b_n, NB, blockIdx.x, hw, hb, hout, 0);
    else
        layer_body(smem, xa_c, xb_c, stat_b_c, perm_a, rowp_a, srcs_ba,
                   w1t1, b11, w2t1, b21, mg1, mb1, uwt1, ub1, ng1, nb1,
                   xa_n, stat_a_n, NA, blockIdx.x - GB, hw, hb, hout, headS);
}

extern "C" void kernel_launch(void* const* d_in, const int* in_sizes, int n_in,
                              void* d_out, int out_size, void* d_ws, size_t ws_size,
                              hipStream_t stream)
{
    const float* x_a_in = (const float*)d_in[0];
    const float* x_b_in = (const float*)d_in[1];
    const int*   e_ab   = (const int*)d_in[2];
    const int*   e_ba   = (const int*)d_in[3];
    const float* pw1    = (const float*)d_in[4];
    const float* pb1    = (const float*)d_in[5];
    const float* pw2    = (const float*)d_in[6];
    const float* pb2    = (const float*)d_in[7];
    const float* mgam   = (const float*)d_in[8];
    const float* mbet   = (const float*)d_in[9];
    const float* uw     = (const float*)d_in[10];
    const float* ubias  = (const float*)d_in[11];
    const float* ngam   = (const float*)d_in[12];
    const float* nbet   = (const float*)d_in[13];
    const float* hw     = (const float*)d_in[14];
    const float* hb     = (const float*)d_in[15];

    const int NA  = in_sizes[0] / CC;
    const int NB  = in_sizes[1] / CC;
    const int Eab = in_sizes[2] / 2;
    const int Eba = in_sizes[3] / 2;

    float* ws = (float*)d_ws;
    size_t off = 0;  // in floats
    ushort* xa0 = (ushort*)(ws + off); off += (size_t)NA * CC / 2;
    ushort* xa1 = (ushort*)(ws + off); off += (size_t)NA * CC / 2;
    ushort* xb0 = (ushort*)(ws + off); off += (size_t)NB * CC / 2;
    ushort* xb1 = (ushort*)(ws + off); off += (size_t)NB * CC / 2;
    float2* sa0 = (float2*)(ws + off); off += (size_t)NA * 2;
    float2* sa1 = (float2*)(ws + off); off += (size_t)NA * 2;
    float2* sb0 = (float2*)(ws + off); off += (size_t)NB * 2;
    float2* sb1 = (float2*)(ws + off); off += (size_t)NB * 2;
    ushort* w1t = (ushort*)(ws + off); off += 4 * 16384 / 2;
    ushort* w2t = (ushort*)(ws + off); off += 4 * 16384 / 2;
    ushort* uwt = (ushort*)(ws + off); off += 4 * 32768 / 2;
    int* iw = (int*)(ws + off);
    size_t ioff = 0;
    int* cnt_b   = iw + ioff; ioff += NB;
    int* cnt_a   = iw + ioff; ioff += NA;
    int* dh      = iw + ioff; ioff += 128;   // contiguous with cnt for one memset
    int* rowp_b  = iw + ioff; ioff += NB + 1;
    int* rowp_a  = iw + ioff; ioff += NA + 1;
    int* off_b   = iw + ioff; ioff += NB;
    int* off_a   = iw + ioff; ioff += NA;
    int* srcs_ab = iw + ioff; ioff += Eab;
    int* srcs_ba = iw + ioff; ioff += Eba;
    const int GbS = (NB + 255) / 256, GaS = (NA + 255) / 256;
    int* part_b  = iw + ioff; ioff += GbS;
    int* part_a  = iw + ioff; ioff += GaS;
    int* dbase   = iw + ioff; ioff += 128;
    int* perm_b  = iw + ioff; ioff += NB;
    int* rank_b  = iw + ioff; ioff += NB;
    int* perm_a  = iw + ioff; ioff += NA;
    int* rank_a  = iw + ioff; ioff += NA;
    int* cnt_sb  = iw + ioff; ioff += NB;
    int* cnt_sa  = iw + ioff; ioff += NA;

    const int GB = (NB + 31) / 32, GA = (NA + 31) / 32;
    const int Ginit = (NA + NB + 7) / 8;
    const int Gwcvt = 1024;
    const int Ghist = (Eab + Eba + 255) / 256;
    const int Gn    = (NA + NB + 255) / 256;

    hipMemsetAsync(cnt_b, 0, (size_t)(NB + NA + 128) * sizeof(int), stream);
    k_setup<<<dim3(Ginit + Gwcvt + Ghist), dim3(256), 0, stream>>>(
        x_a_in, xa0, sa0, NA, x_b_in, xb0, sb0, NB,
        pw1, pw2, uw, w1t, w2t, uwt,
        e_ab + Eab, Eab, cnt_b, e_ba + Eba, Eba, cnt_a,
        Ginit, Gwcvt);
    k_dhist<<<dim3(Gn), dim3(256), 0, stream>>>(cnt_b, NB, cnt_a, NA, dh);
    k_dscan<<<dim3(1), dim3(128), 0, stream>>>(dh, dbase);
    k_dperm<<<dim3(Gn), dim3(256), 0, stream>>>(
        cnt_b, NB, dbase, perm_b, rank_b, cnt_sb,
        cnt_a, NA, perm_a, rank_a, cnt_sa);
    k_scanA<<<dim3(GbS + GaS), dim3(256), 0, stream>>>(
        cnt_sb, rowp_b, part_b, NB, GbS, cnt_sa, rowp_a, part_a, NA);
    k_scanB<<<dim3(GbS + GaS), dim3(256), 0, stream>>>(
        rowp_b, part_b, off_b, NB, GbS, rowp_a, part_a, off_a, NA);
    k_scatter_dual<<<dim3((Eab + Eba + 255) / 256), dim3(256), 0, stream>>>(
        e_ab, e_ab + Eab, Eab, rank_b, off_b, srcs_ab,
        e_ba, e_ba + Eba, Eba, rank_a, off_a, srcs_ba);

    ushort* xac = xa0; ushort* xan = xa1;
    ushort* xbc = xb0; ushort* xbn = xb1;
    float2* sac = sa0; float2* san = sa1;
    float2* sbc = sb0; float2* sbn = sb1;

    for (int lyr = 0; lyr < 2; ++lyr) {
        int t0 = lyr * 2 + 0;   // conv a->b (dst = b)
        int t1 = lyr * 2 + 1;   // conv b->a (dst = a)
        int headS = (lyr == 1) ? out_size : 0;

        k_layer_dual<<<dim3(GB + GA), dim3(512), 0, stream>>>(
            xbc, xac, sac, sbc,
            perm_b, perm_a,
            rowp_b, srcs_ab, rowp_a, srcs_ba,
            xbn, xan, sbn, san,
            NB, NA, GB,
            w1t + (size_t)t0 * 16384, pb1 + t0 * CC, w2t + (size_t)t0 * 16384, pb2 + t0 * CC,
            mgam + t0 * CC, mbet + t0 * CC,
            uwt + (size_t)t0 * 32768, ubias + t0 * CC, ngam + t0 * CC, nbet + t0 * CC,
            w1t + (size_t)t1 * 16384, pb1 + t1 * CC, w2t + (size_t)t1 * 16384, pb2 + t1 * CC,
            mgam + t1 * CC, mbet + t1 * CC,
            uwt + (size_t)t1 * 32768, ubias + t1 * CC, ngam + t1 * CC, nbet + t1 * CC,
            hw, hb, (float*)d_out, headS);

        ushort* t;
        t = xac; xac = xan; xan = t;
        t = xbc; xbc = xbn; xbn = t;
        float2* s;
        s = sac; sac = san; san = s;
        s = sbc; sbc = sbn; sbn = s;
    }
}

// Round 15
// 224.991 us; speedup vs baseline: 2.0229x; 2.0229x over previous
//
#include <hip/hip_runtime.h>

#define CC 128
#define ECAP 512

typedef __attribute__((ext_vector_type(8))) short bf16x8;
typedef __attribute__((ext_vector_type(4))) float f32x4;
#define MFMA16(a, b, c) __builtin_amdgcn_mfma_f32_16x16x32_bf16(a, b, c, 0, 0, 0)

__device__ __forceinline__ float enc_nan(float v) {
    if (v != v) return 0.f;
    if (v > 3.0e38f) return 1.f;
    if (v < -3.0e38f) return -1.f;
    return v;
}

__device__ __forceinline__ ushort f2bf(float x) {
    unsigned u = __builtin_bit_cast(unsigned, x);
    u += 0x7fff + ((u >> 16) & 1);
    return (ushort)(u >> 16);
}
__device__ __forceinline__ float bf2f(ushort h) {
    return __builtin_bit_cast(float, ((unsigned)h) << 16);
}

__device__ __forceinline__ int swz128(int row, int k) { return (row * 128 + k) ^ ((row & 7) << 3); }

// ---------- fused setup: init(a,b) | weight-cvt | edge histogram ----------
__global__ __launch_bounds__(256)
void k_setup(const float* __restrict__ xa_in, ushort* __restrict__ xa,
             float2* __restrict__ stat_a, int NA,
             const float* __restrict__ xb_in, ushort* __restrict__ xb,
             float2* __restrict__ stat_b, int NB,
             const float* __restrict__ pw1, const float* __restrict__ pw2,
             const float* __restrict__ uw,
             ushort* __restrict__ w1t, ushort* __restrict__ w2t, ushort* __restrict__ uwt,
             const int* __restrict__ dst_b, int Eab, int* __restrict__ cnt_b,
             const int* __restrict__ dst_a, int Eba, int* __restrict__ cnt_a,
             int Ginit, int Gwcvt)
{
    const int b = blockIdx.x;
    const int tid = threadIdx.x;
    if (b < Ginit) {
        int row = b * 8 + (tid >> 5);
        int s = tid & 31;
        const float* xin; ushort* xo; float2* st;
        if (row < NA) { xin = xa_in; xo = xa; st = stat_a; }
        else {
            row -= NA;
            if (row >= NB) return;
            xin = xb_in; xo = xb; st = stat_b;
        }
        float4 v = *reinterpret_cast<const float4*>(xin + (size_t)row * CC + s * 4);
        ushort h0 = f2bf(enc_nan(v.x)), h1 = f2bf(enc_nan(v.y));
        ushort h2 = f2bf(enc_nan(v.z)), h3 = f2bf(enc_nan(v.w));
        *reinterpret_cast<ushort4*>(xo + (size_t)row * CC + s * 4) = make_ushort4(h0, h1, h2, h3);
        float r0 = bf2f(h0), r1 = bf2f(h1), r2 = bf2f(h2), r3 = bf2f(h3);
        float sm = (r0 + r1) + (r2 + r3);
        float sq = fmaf(r0, r0, fmaf(r1, r1, fmaf(r2, r2, r3 * r3)));
        #pragma unroll
        for (int m = 1; m < 32; m <<= 1) { sm += __shfl_xor(sm, m); sq += __shfl_xor(sq, m); }
        if (s == 0) st[row] = make_float2(sm, sq);
    } else if (b < Ginit + Gwcvt) {
        int i = (b - Ginit) * 256 + tid;   // 4 types x 65536
        int t = i >> 16;
        int r = i & 65535;
        if (r < 16384) {
            int k = r >> 7, c = r & 127;
            w1t[(size_t)t * 16384 + c * 128 + k] = f2bf(pw1[(size_t)t * 16384 + k * 128 + c]);
        } else if (r < 32768) {
            int rr = r - 16384;
            int k = rr >> 7, c = rr & 127;
            w2t[(size_t)t * 16384 + c * 128 + k] = f2bf(pw2[(size_t)t * 16384 + k * 128 + c]);
        } else {
            int rr = r - 32768;
            int k = rr >> 7, c = rr & 127;
            uwt[(size_t)t * 32768 + c * 256 + k] = f2bf(uw[(size_t)t * 32768 + k * 128 + c]);
        }
    } else {
        int i = (b - Ginit - Gwcvt) * 256 + tid;
        if (i < Eab) atomicAdd(&cnt_b[dst_b[i]], 1);
        else if (i - Eab < Eba) atomicAdd(&cnt_a[dst_a[i - Eab]], 1);
    }
}

// ---------- degree-sort: LDS-aggregated histogram ----------
__global__ __launch_bounds__(256)
void k_dhist(const int* __restrict__ cnt_b, int NB, const int* __restrict__ cnt_a, int NA,
             int* __restrict__ dh)
{
    __shared__ int lh[128];
    const int tid = threadIdx.x;
    if (tid < 128) lh[tid] = 0;
    __syncthreads();
    int i = blockIdx.x * 256 + tid;
    if (i < NB) {
        int d = cnt_b[i]; if (d > 63) d = 63;
        atomicAdd(&lh[d], 1);
    } else if (i - NB < NA) {
        int d = cnt_a[i - NB]; if (d > 63) d = 63;
        atomicAdd(&lh[64 + d], 1);
    }
    __syncthreads();
    if (tid < 128 && lh[tid] > 0) atomicAdd(&dh[tid], lh[tid]);
}

__global__ __launch_bounds__(128)
void k_dscan(const int* __restrict__ dh, int* __restrict__ dbase)
{
    const int tid = threadIdx.x, lane = tid & 63;
    int v = dh[tid];
    int incl = v;
    #pragma unroll
    for (int d = 1; d < 64; d <<= 1) {
        int t = __shfl_up(incl, d);
        if (lane >= d) incl += t;
    }
    dbase[tid] = incl - v;   // exclusive, per 64-entry segment
}

// ---------- degree-sort: per-block range reservation + intra-block rank ----------
__global__ __launch_bounds__(256)
void k_dperm(const int* __restrict__ cnt_b, int NB, int* __restrict__ dbase,
             int* __restrict__ perm_b, int* __restrict__ rank_b, int* __restrict__ cnt_sb,
             const int* __restrict__ cnt_a, int NA,
             int* __restrict__ perm_a, int* __restrict__ rank_a, int* __restrict__ cnt_sa)
{
    __shared__ int lh[128];
    __shared__ int lbase[128];
    const int tid = threadIdx.x;
    if (tid < 128) lh[tid] = 0;
    __syncthreads();
    const int i = blockIdx.x * 256 + tid;
    int bucket = -1, deg = 0, myloc = 0;
    bool isB = false;
    int node = -1;
    if (i < NB) {
        isB = true; node = i;
        deg = cnt_b[i];
        int d = deg > 63 ? 63 : deg;
        bucket = d;
        myloc = atomicAdd(&lh[bucket], 1);
    } else if (i - NB < NA) {
        node = i - NB;
        deg = cnt_a[node];
        int d = deg > 63 ? 63 : deg;
        bucket = 64 + d;
        myloc = atomicAdd(&lh[bucket], 1);
    }
    __syncthreads();
    if (tid < 128 && lh[tid] > 0) lbase[tid] = atomicAdd(&dbase[tid], lh[tid]);
    __syncthreads();
    if (bucket >= 0) {
        int r = lbase[bucket] + myloc;
        if (isB) { perm_b[r] = node; rank_b[node] = r; cnt_sb[r] = deg; }
        else     { perm_a[r] = node; rank_a[node] = r; cnt_sa[r] = deg; }
    }
}

// ---------- parallel scan, phase A ----------
__global__ __launch_bounds__(256)
void k_scanA(const int* __restrict__ cnt0, int* __restrict__ rowp0, int* __restrict__ part0,
             int n0, int Gb0,
             const int* __restrict__ cnt1, int* __restrict__ rowp1, int* __restrict__ part1, int n1)
{
    const int b = blockIdx.x;
    const bool sel = b < Gb0;
    const int* cnt = sel ? cnt0 : cnt1;
    int* rowp      = sel ? rowp0 : rowp1;
    int* part      = sel ? part0 : part1;
    const int n    = sel ? n0 : n1;
    const int bb   = sel ? b : b - Gb0;

    __shared__ int wsum[4];
    const int tid = threadIdx.x, lane = tid & 63, wid = tid >> 6;
    const int i = bb * 256 + tid;
    int v = (i < n) ? cnt[i] : 0;
    int incl = v;
    #pragma unroll
    for (int d = 1; d < 64; d <<= 1) {
        int t = __shfl_up(incl, d);
        if (lane >= d) incl += t;
    }
    if (lane == 63) wsum[wid] = incl;
    __syncthreads();
    int base = 0;
    #pragma unroll
    for (int j = 0; j < 4; ++j) if (j < wid) base += wsum[j];
    int excl = base + incl - v;
    if (i < n) rowp[i] = excl;
    if (tid == 255) part[bb] = excl + v;
}

// ---------- parallel scan, phase B ----------
__global__ __launch_bounds__(256)
void k_scanB(int* __restrict__ rowp0, const int* __restrict__ part0, int* __restrict__ off0,
             int n0, int Gb0,
             int* __restrict__ rowp1, const int* __restrict__ part1, int* __restrict__ off1, int n1)
{
    const int b = blockIdx.x;
    const bool sel = b < Gb0;
    int* rowp       = sel ? rowp0 : rowp1;
    const int* part = sel ? part0 : part1;
    int* off        = sel ? off0 : off1;
    const int n     = sel ? n0 : n1;
    const int bb    = sel ? b : b - Gb0;
    const int Gl    = sel ? Gb0 : (int)gridDim.x - Gb0;

    __shared__ int base_s;
    const int tid = threadIdx.x;
    if (tid < 64) {
        int s = 0;
        for (int j = tid; j < bb; j += 64) s += part[j];
        #pragma unroll
        for (int m = 1; m < 64; m <<= 1) s += __shfl_xor(s, m);
        if (tid == 0) base_s = s;
    }
    __syncthreads();
    const int base = base_s;
    const int i = bb * 256 + tid;
    if (i < n) {
        int r = rowp[i] + base;
        rowp[i] = r;
        off[i] = r;
    }
    if (bb == Gl - 1 && tid == 0) rowp[n] = base + part[bb];
}

// ---------- edge scatter into sorted CSR (via rank) ----------
__global__ __launch_bounds__(256)
void k_scatter_dual(const int* __restrict__ src_b, const int* __restrict__ dst_b, int Eab,
                    const int* __restrict__ rank_b, int* __restrict__ off_b, int* __restrict__ srcs_ab,
                    const int* __restrict__ src_a, const int* __restrict__ dst_a, int Eba,
                    const int* __restrict__ rank_a, int* __restrict__ off_a, int* __restrict__ srcs_ba)
{
    int i = blockIdx.x * 256 + threadIdx.x;
    if (i < Eab) {
        int p = atomicAdd(&off_b[rank_b[dst_b[i]]], 1);
        srcs_ab[p] = src_b[i];
    } else if (i - Eab < Eba) {
        int j = i - Eab;
        int p = atomicAdd(&off_a[rank_a[dst_a[j]]], 1);
        srcs_ba[p] = src_a[j];
    }
}

// ---------- fully fused conv: 32-node (degree-sorted) tile, 8 waves ----------
__device__ __forceinline__ void layer_body(
    char* smem,
    const ushort* __restrict__ xdst, const ushort* __restrict__ xsrc,
    const float2* __restrict__ stat_src, const int* __restrict__ perm,
    const int* __restrict__ rowp, const int* __restrict__ srcs,
    const ushort* __restrict__ w1t, const float* __restrict__ b1,
    const ushort* __restrict__ w2t, const float* __restrict__ b2,
    const float* __restrict__ mg, const float* __restrict__ mbt,
    const ushort* __restrict__ uwt, const float* __restrict__ ub,
    const float* __restrict__ ng, const float* __restrict__ nb,
    ushort* __restrict__ xout, float2* __restrict__ statOut, int N, int blk,
    const float* __restrict__ hw, const float* __restrict__ hb,
    float* __restrict__ hout, int headS)
{
    ushort* As = (ushort*)smem;              // 32x128 bf16, swizzled (x_dst, sorted order)
    ushort* Hs = (ushort*)(smem + 8192);     // 32x128 bf16, swizzled (relu(h), then agg)
    ushort* P  = (ushort*)(smem + 16384);    // 32x128 bf16, linear (pred)
    float (*os)[CC + 4] = (float(*)[CC + 4])(smem + 8192);  // overlays Hs+P after update GEMM
    int* sL   = (int*)(smem + 25088);        // block srcs slice (ECAP ints)
    int* shrp = (int*)(smem + 25088 + ECAP * 4);  // 33-entry rowp slice

    const int tid = threadIdx.x;
    const int base = blk * 32;
    const int w = tid >> 6, l = tid & 63;
    const int lr = l & 15, lg = l >> 4;

    if (tid < 33) {
        int nn = base + tid;
        shrp[tid] = rowp[nn < N ? nn : N];
    }
    {   // stage x_dst (permuted rows) -> As (swizzled): one bf16x8 per thread
        int row = tid >> 4, k0 = (tid & 15) << 3;
        int pnode = base + row;
        bf16x8 v0 = {};
        if (pnode < N) {
            int anode = perm[pnode];
            v0 = *reinterpret_cast<const bf16x8*>(xdst + (size_t)anode * CC + k0);
        }
        *reinterpret_cast<bf16x8*>(&As[swz128(row, k0)]) = v0;
    }
    // stage the block's srcs slice (wave-uniform bounds; one int per thread)
    const int jb0 = rowp[base];
    {
        int top = base + 32; if (top > N) top = N;
        const int je0 = rowp[top];
        int ec = je0 - jb0; if (ec > ECAP) ec = ECAP;
        if (tid < ec) sL[tid] = srcs[jb0 + tid];
    }
    __syncthreads();

    // pred GEMM1: Hs = relu(As @ w1 + b1); wave w owns cols [w*16, w*16+16)
    {
        f32x4 acc[2] = {};
        for (int kb = 0; kb < 4; ++kb) {
            int k = kb * 32 + lg * 8;
            bf16x8 a0 = *reinterpret_cast<const bf16x8*>(&As[swz128(lr, k)]);
            bf16x8 a1 = *reinterpret_cast<const bf16x8*>(&As[swz128(lr + 16, k)]);
            bf16x8 b0 = *reinterpret_cast<const bf16x8*>(&w1t[(size_t)(w * 16 + lr) * 128 + k]);
            acc[0] = MFMA16(a0, b0, acc[0]);
            acc[1] = MFMA16(a1, b0, acc[1]);
        }
        float bc = b1[w * 16 + lr];
        int col = w * 16 + lr;
        #pragma unroll
        for (int mi = 0; mi < 2; ++mi)
            #pragma unroll
            for (int j = 0; j < 4; ++j) {
                int row = mi * 16 + lg * 4 + j;
                Hs[swz128(row, col)] = f2bf(fmaxf(acc[mi][j] + bc, 0.f));
            }
    }
    __syncthreads();

    // pred GEMM2: P = Hs @ w2 + b2  (linear layout)
    {
        f32x4 acc[2] = {};
        for (int kb = 0; kb < 4; ++kb) {
            int k = kb * 32 + lg * 8;
            bf16x8 a0 = *reinterpret_cast<const bf16x8*>(&Hs[swz128(lr, k)]);
            bf16x8 a1 = *reinterpret_cast<const bf16x8*>(&Hs[swz128(lr + 16, k)]);
            bf16x8 b0 = *reinterpret_cast<const bf16x8*>(&w2t[(size_t)(w * 16 + lr) * 128 + k]);
            acc[0] = MFMA16(a0, b0, acc[0]);
            acc[1] = MFMA16(a1, b0, acc[1]);
        }
        float bc = b2[w * 16 + lr];
        int col = w * 16 + lr;
        #pragma unroll
        for (int mi = 0; mi < 2; ++mi)
            #pragma unroll
            for (int j = 0; j < 4; ++j) {
                int row = mi * 16 + lg * 4 + j;
                P[row * CC + col] = f2bf(acc[mi][j] + bc);
            }
    }
    __syncthreads();

    // agg phase: wave w owns sorted nodes w*4..w*4+3; quarter-wave = 4 edges in flight
    {
        const int quarter = l >> 4;
        const int c = (l & 15) * 8;
        const float4 g0 = *reinterpret_cast<const float4*>(mg + c);
        const float4 g1 = *reinterpret_cast<const float4*>(mg + c + 4);
        const float4 e0 = *reinterpret_cast<const float4*>(mbt + c);
        const float4 e1 = *reinterpret_cast<const float4*>(mbt + c + 4);
        const float gv[8] = { g0.x, g0.y, g0.z, g0.w, g1.x, g1.y, g1.z, g1.w };
        const float bv[8] = { e0.x, e0.y, e0.z, e0.w, e1.x, e1.y, e1.z, e1.w };
        for (int i = 0; i < 4; ++i) {
            const int nl_ = w * 4 + i;
            const int d = base + nl_;
            if (d >= N) break;
            bf16x8 prb = *reinterpret_cast<const bf16x8*>(&P[nl_ * CC + c]);
            float pr[8];
            #pragma unroll
            for (int q = 0; q < 8; ++q) pr[q] = bf2f((ushort)prb[q]);
            float sp = 0.f, qp = 0.f;
            #pragma unroll
            for (int q = 0; q < 8; ++q) { sp += pr[q]; qp = fmaf(pr[q], pr[q], qp); }
            #pragma unroll
            for (int m = 1; m < 16; m <<= 1) { sp += __shfl_xor(sp, m); qp += __shfl_xor(qp, m); }
            const int jb = shrp[nl_], je = shrp[nl_ + 1];
            const int deg = je - jb;
            float a[8] = {};
            float rsum = 0.f, cmsum = 0.f;
            for (int j = jb + quarter; j < je; j += 4) {
                const int le = j - jb0;
                const int sidx = (le < ECAP) ? sL[le] : srcs[j];
                bf16x8 xb_ = *reinterpret_cast<const bf16x8*>(xsrc + (size_t)sidx * CC + c);
                const float2 st = stat_src[sidx];
                float xj[8];
                #pragma unroll
                for (int q = 0; q < 8; ++q) xj[q] = bf2f((ushort)xb_[q]);
                float dA = 0.f, dB = 0.f;
                #pragma unroll
                for (int q = 0; q < 4; ++q) dA = fmaf(xj[q], pr[q], dA);
                #pragma unroll
                for (int q = 4; q < 8; ++q) dB = fmaf(xj[q], pr[q], dB);
                float dot = dA + dB;
                #pragma unroll
                for (int m = 1; m < 16; m <<= 1) dot += __shfl_xor(dot, m);
                const float mean = (st.x - sp) * (1.f / 128.f);
                const float var = fmaf(-2.f, dot, st.y + qp) * (1.f / 128.f) - mean * mean;
                const float r = rsqrtf(var + 1e-5f);
                rsum += r;
                cmsum = fmaf(mean, r, cmsum);
                #pragma unroll
                for (int q = 0; q < 8; ++q) a[q] = fmaf(xj[q], r, a[q]);
            }
            #pragma unroll
            for (int q = 0; q < 8; ++q) { a[q] += __shfl_xor(a[q], 16); a[q] += __shfl_xor(a[q], 32); }
            rsum += __shfl_xor(rsum, 16);  rsum += __shfl_xor(rsum, 32);
            cmsum += __shfl_xor(cmsum, 16); cmsum += __shfl_xor(cmsum, 32);
            if (quarter == 0) {
                ushort o8[8];
                if (deg > 0) {
                    const float inv = 1.f / (float)deg;
                    #pragma unroll
                    for (int q = 0; q < 8; ++q)
                        o8[q] = f2bf(fmaf((a[q] - pr[q] * rsum - cmsum) * inv, gv[q], bv[q]));
                } else {
                    #pragma unroll
                    for (int q = 0; q < 8; ++q) o8[q] = 0;
                }
                *reinterpret_cast<bf16x8*>(&Hs[swz128(nl_, c)]) = *reinterpret_cast<bf16x8*>(&o8[0]);
            }
        }
    }
    __syncthreads();

    // update GEMM: concat(x=As | agg=Hs) @ uwt + ub, K=256; wave w owns 16 cols
    f32x4 acc[2] = {};
    for (int kb = 0; kb < 8; ++kb) {
        int k = kb * 32 + lg * 8;
        const ushort* Ab = (k < 128) ? As : Hs;
        int kl = k & 127;
        bf16x8 a0 = *reinterpret_cast<const bf16x8*>(&Ab[swz128(lr, kl)]);
        bf16x8 a1 = *reinterpret_cast<const bf16x8*>(&Ab[swz128(lr + 16, kl)]);
        bf16x8 b0 = *reinterpret_cast<const bf16x8*>(&uwt[(size_t)(w * 16 + lr) * 256 + k]);
        acc[0] = MFMA16(a0, b0, acc[0]);
        acc[1] = MFMA16(a1, b0, acc[1]);
    }
    __syncthreads();   // all reads of As/Hs done before os overlays them

    {
        float bc = ub[w * 16 + lr];
        int col = w * 16 + lr;
        #pragma unroll
        for (int mi = 0; mi < 2; ++mi)
            #pragma unroll
            for (int j = 0; j < 4; ++j) {
                int row = mi * 16 + lg * 4 + j;
                os[row][col] = fmaxf(acc[mi][j] + bc, 0.f);
            }
    }
    __syncthreads();

    // node LayerNorm + relu + stats (+head); 16 lanes/node, 8 channels/lane
    const int nl = tid >> 4;
    const int cl = tid & 15;
    float vals[8];
    float sm = 0.f, sq = 0.f;
    #pragma unroll
    for (int t = 0; t < 8; ++t) {
        float u = os[nl][cl + 16 * t];
        vals[t] = u; sm += u; sq = fmaf(u, u, sq);
    }
    #pragma unroll
    for (int m = 1; m < 16; m <<= 1) { sm += __shfl_xor(sm, m); sq += __shfl_xor(sq, m); }
    float mean = sm * (1.f / 128.f);
    float var = sq * (1.f / 128.f) - mean * mean;
    float r = rsqrtf(var + 1e-5f);
    int pnode = base + nl;
    if (pnode < N) {
        const int anode = perm[pnode];
        float so = 0.f, sqo = 0.f, hsum = 0.f;
        bool doHead = (anode < headS);
        #pragma unroll
        for (int t = 0; t < 8; ++t) {
            int cch = cl + 16 * t;
            float o = fmaxf(fmaf((vals[t] - mean) * r, ng[cch], nb[cch]), 0.f);
            ushort ob = f2bf(o);
            xout[(size_t)anode * CC + cch] = ob;
            float orr = bf2f(ob);
            so += orr; sqo = fmaf(orr, orr, sqo);
            if (doHead) hsum = fmaf(o, hw[cch], hsum);
        }
        #pragma unroll
        for (int m = 1; m < 16; m <<= 1) { so += __shfl_xor(so, m); sqo += __shfl_xor(sqo, m); }
        if (doHead) {
            #pragma unroll
            for (int m = 1; m < 16; m <<= 1) hsum += __shfl_xor(hsum, m);
            if (cl == 0) hout[anode] = hsum + hb[0];
        }
        if (cl == 0) statOut[anode] = make_float2(so, sqo);
    }
}

__global__ __launch_bounds__(512)
void k_layer_dual(
    const ushort* __restrict__ xb_c, const ushort* __restrict__ xa_c,
    const float2* __restrict__ stat_a_c, const float2* __restrict__ stat_b_c,
    const int* __restrict__ perm_b, const int* __restrict__ perm_a,
    const int* __restrict__ rowp_b, const int* __restrict__ srcs_ab,
    const int* __restrict__ rowp_a, const int* __restrict__ srcs_ba,
    ushort* __restrict__ xb_n, ushort* __restrict__ xa_n,
    float2* __restrict__ stat_b_n, float2* __restrict__ stat_a_n,
    int NB, int NA, int GB,
    const ushort* __restrict__ w1t0, const float* __restrict__ b10,
    const ushort* __restrict__ w2t0, const float* __restrict__ b20,
    const float* __restrict__ mg0, const float* __restrict__ mb0,
    const ushort* __restrict__ uwt0, const float* __restrict__ ub0,
    const float* __restrict__ ng0, const float* __restrict__ nb0,
    const ushort* __restrict__ w1t1, const float* __restrict__ b11,
    const ushort* __restrict__ w2t1, const float* __restrict__ b21,
    const float* __restrict__ mg1, const float* __restrict__ mb1,
    const ushort* __restrict__ uwt1, const float* __restrict__ ub1,
    const float* __restrict__ ng1, const float* __restrict__ nb1,
    const float* __restrict__ hw, const float* __restrict__ hb,
    float* __restrict__ hout, int headS)
{
    __shared__ __align__(16) char smem[25088 + ECAP * 4 + 144];
    if ((int)blockIdx.x < GB)
        layer_body(smem, xb_c, xa_c, stat_a_c, perm_b, rowp_b, srcs_ab,
                   w1t0, b10, w2t0, b20, mg0, mb0, uwt0, ub0, ng0, nb0,
                   xb_n, stat_b_n, NB, blockIdx.x, hw, hb, hout, 0);
    else
        layer_body(smem, xa_c, xb_c, stat_b_c, perm_a, rowp_a, srcs_ba,
                   w1t1, b11, w2t1, b21, mg1, mb1, uwt1, ub1, ng1, nb1,
                   xa_n, stat_a_n, NA, blockIdx.x - GB, hw, hb, hout, headS);
}

extern "C" void kernel_launch(void* const* d_in, const int* in_sizes, int n_in,
                              void* d_out, int out_size, void* d_ws, size_t ws_size,
                              hipStream_t stream)
{
    const float* x_a_in = (const float*)d_in[0];
    const float* x_b_in = (const float*)d_in[1];
    const int*   e_ab   = (const int*)d_in[2];
    const int*   e_ba   = (const int*)d_in[3];
    const float* pw1    = (const float*)d_in[4];
    const float* pb1    = (const float*)d_in[5];
    const float* pw2    = (const float*)d_in[6];
    const float* pb2    = (const float*)d_in[7];
    const float* mgam   = (const float*)d_in[8];
    const float* mbet   = (const float*)d_in[9];
    const float* uw     = (const float*)d_in[10];
    const float* ubias  = (const float*)d_in[11];
    const float* ngam   = (const float*)d_in[12];
    const float* nbet   = (const float*)d_in[13];
    const float* hw     = (const float*)d_in[14];
    const float* hb     = (const float*)d_in[15];

    const int NA  = in_sizes[0] / CC;
    const int NB  = in_sizes[1] / CC;
    const int Eab = in_sizes[2] / 2;
    const int Eba = in_sizes[3] / 2;

    float* ws = (float*)d_ws;
    size_t off = 0;  // in floats
    ushort* xa0 = (ushort*)(ws + off); off += (size_t)NA * CC / 2;
    ushort* xa1 = (ushort*)(ws + off); off += (size_t)NA * CC / 2;
    ushort* xb0 = (ushort*)(ws + off); off += (size_t)NB * CC / 2;
    ushort* xb1 = (ushort*)(ws + off); off += (size_t)NB * CC / 2;
    float2* sa0 = (float2*)(ws + off); off += (size_t)NA * 2;
    float2* sa1 = (float2*)(ws + off); off += (size_t)NA * 2;
    float2* sb0 = (float2*)(ws + off); off += (size_t)NB * 2;
    float2* sb1 = (float2*)(ws + off); off += (size_t)NB * 2;
    ushort* w1t = (ushort*)(ws + off); off += 4 * 16384 / 2;
    ushort* w2t = (ushort*)(ws + off); off += 4 * 16384 / 2;
    ushort* uwt = (ushort*)(ws + off); off += 4 * 32768 / 2;
    int* iw = (int*)(ws + off);
    size_t ioff = 0;
    int* cnt_b   = iw + ioff; ioff += NB;
    int* cnt_a   = iw + ioff; ioff += NA;
    int* dh      = iw + ioff; ioff += 128;   // contiguous with cnt for one memset
    int* rowp_b  = iw + ioff; ioff += NB + 1;
    int* rowp_a  = iw + ioff; ioff += NA + 1;
    int* off_b   = iw + ioff; ioff += NB;
    int* off_a   = iw + ioff; ioff += NA;
    int* srcs_ab = iw + ioff; ioff += Eab;
    int* srcs_ba = iw + ioff; ioff += Eba;
    const int GbS = (NB + 255) / 256, GaS = (NA + 255) / 256;
    int* part_b  = iw + ioff; ioff += GbS;
    int* part_a  = iw + ioff; ioff += GaS;
    int* dbase   = iw + ioff; ioff += 128;
    int* perm_b  = iw + ioff; ioff += NB;
    int* rank_b  = iw + ioff; ioff += NB;
    int* perm_a  = iw + ioff; ioff += NA;
    int* rank_a  = iw + ioff; ioff += NA;
    int* cnt_sb  = iw + ioff; ioff += NB;
    int* cnt_sa  = iw + ioff; ioff += NA;

    const int GB = (NB + 31) / 32, GA = (NA + 31) / 32;
    const int Ginit = (NA + NB + 7) / 8;
    const int Gwcvt = 1024;
    const int Ghist = (Eab + Eba + 255) / 256;
    const int Gn    = (NA + NB + 255) / 256;

    hipMemsetAsync(cnt_b, 0, (size_t)(NB + NA + 128) * sizeof(int), stream);
    k_setup<<<dim3(Ginit + Gwcvt + Ghist), dim3(256), 0, stream>>>(
        x_a_in, xa0, sa0, NA, x_b_in, xb0, sb0, NB,
        pw1, pw2, uw, w1t, w2t, uwt,
        e_ab + Eab, Eab, cnt_b, e_ba + Eba, Eba, cnt_a,
        Ginit, Gwcvt);
    k_dhist<<<dim3(Gn), dim3(256), 0, stream>>>(cnt_b, NB, cnt_a, NA, dh);
    k_dscan<<<dim3(1), dim3(128), 0, stream>>>(dh, dbase);
    k_dperm<<<dim3(Gn), dim3(256), 0, stream>>>(
        cnt_b, NB, dbase, perm_b, rank_b, cnt_sb,
        cnt_a, NA, perm_a, rank_a, cnt_sa);
    k_scanA<<<dim3(GbS + GaS), dim3(256), 0, stream>>>(
        cnt_sb, rowp_b, part_b, NB, GbS, cnt_sa, rowp_a, part_a, NA);
    k_scanB<<<dim3(GbS + GaS), dim3(256), 0, stream>>>(
        rowp_b, part_b, off_b, NB, GbS, rowp_a, part_a, off_a, NA);
    k_scatter_dual<<<dim3((Eab + Eba + 255) / 256), dim3(256), 0, stream>>>(
        e_ab, e_ab + Eab, Eab, rank_b, off_b, srcs_ab,
        e_ba, e_ba + Eba, Eba, rank_a, off_a, srcs_ba);

    ushort* xac = xa0; ushort* xan = xa1;
    ushort* xbc = xb0; ushort* xbn = xb1;
    float2* sac = sa0; float2* san = sa1;
    float2* sbc = sb0; float2* sbn = sb1;

    for (int lyr = 0; lyr < 2; ++lyr) {
        int t0 = lyr * 2 + 0;   // conv a->b (dst = b)
        int t1 = lyr * 2 + 1;   // conv b->a (dst = a)
        int headS = (lyr == 1) ? out_size : 0;

        k_layer_dual<<<dim3(GB + GA), dim3(512), 0, stream>>>(
            xbc, xac, sac, sbc,
            perm_b, perm_a,
            rowp_b, srcs_ab, rowp_a, srcs_ba,
            xbn, xan, sbn, san,
            NB, NA, GB,
            w1t + (size_t)t0 * 16384, pb1 + t0 * CC, w2t + (size_t)t0 * 16384, pb2 + t0 * CC,
            mgam + t0 * CC, mbet + t0 * CC,
            uwt + (size_t)t0 * 32768, ubias + t0 * CC, ngam + t0 * CC, nbet + t0 * CC,
            w1t + (size_t)t1 * 16384, pb1 + t1 * CC, w2t + (size_t)t1 * 16384, pb2 + t1 * CC,
            mgam + t1 * CC, mbet + t1 * CC,
            uwt + (size_t)t1 * 32768, ubias + t1 * CC, ngam + t1 * CC, nbet + t1 * CC,
            hw, hb, (float*)d_out, headS);

        ushort* t;
        t = xac; xac = xan; xan = t;
        t = xbc; xbc = xbn; xbn = t;
        float2* s;
        s = sac; sac = san; san = s;
        s = sbc; sbc = sbn; sbn = s;
    }
}

// Round 16
// 207.602 us; speedup vs baseline: 2.1923x; 1.0838x over previous
//
#include <hip/hip_runtime.h>

#define CC 128
#define ECAP 512

typedef __attribute__((ext_vector_type(8))) short bf16x8;
typedef __attribute__((ext_vector_type(4))) float f32x4;
#define MFMA16(a, b, c) __builtin_amdgcn_mfma_f32_16x16x32_bf16(a, b, c, 0, 0, 0)

__device__ __forceinline__ float enc_nan(float v) {
    if (v != v) return 0.f;
    if (v > 3.0e38f) return 1.f;
    if (v < -3.0e38f) return -1.f;
    return v;
}

__device__ __forceinline__ ushort f2bf(float x) {
    unsigned u = __builtin_bit_cast(unsigned, x);
    u += 0x7fff + ((u >> 16) & 1);
    return (ushort)(u >> 16);
}
__device__ __forceinline__ float bf2f(ushort h) {
    return __builtin_bit_cast(float, ((unsigned)h) << 16);
}

__device__ __forceinline__ int swz128(int row, int k) { return (row * 128 + k) ^ ((row & 7) << 3); }

// ---------- fused setup: init(a,b) | weight-cvt | edge histogram ----------
__global__ __launch_bounds__(256)
void k_setup(const float* __restrict__ xa_in, ushort* __restrict__ xa,
             float2* __restrict__ stat_a, int NA,
             const float* __restrict__ xb_in, ushort* __restrict__ xb,
             float2* __restrict__ stat_b, int NB,
             const float* __restrict__ pw1, const float* __restrict__ pw2,
             const float* __restrict__ uw,
             ushort* __restrict__ w1t, ushort* __restrict__ w2t, ushort* __restrict__ uwt,
             const int* __restrict__ dst_b, int Eab, int* __restrict__ cnt_b,
             const int* __restrict__ dst_a, int Eba, int* __restrict__ cnt_a,
             int Ginit, int Gwcvt)
{
    const int b = blockIdx.x;
    const int tid = threadIdx.x;
    if (b < Ginit) {
        int row = b * 8 + (tid >> 5);
        int s = tid & 31;
        const float* xin; ushort* xo; float2* st;
        if (row < NA) { xin = xa_in; xo = xa; st = stat_a; }
        else {
            row -= NA;
            if (row >= NB) return;
            xin = xb_in; xo = xb; st = stat_b;
        }
        float4 v = *reinterpret_cast<const float4*>(xin + (size_t)row * CC + s * 4);
        ushort h0 = f2bf(enc_nan(v.x)), h1 = f2bf(enc_nan(v.y));
        ushort h2 = f2bf(enc_nan(v.z)), h3 = f2bf(enc_nan(v.w));
        *reinterpret_cast<ushort4*>(xo + (size_t)row * CC + s * 4) = make_ushort4(h0, h1, h2, h3);
        float r0 = bf2f(h0), r1 = bf2f(h1), r2 = bf2f(h2), r3 = bf2f(h3);
        float sm = (r0 + r1) + (r2 + r3);
        float sq = fmaf(r0, r0, fmaf(r1, r1, fmaf(r2, r2, r3 * r3)));
        #pragma unroll
        for (int m = 1; m < 32; m <<= 1) { sm += __shfl_xor(sm, m); sq += __shfl_xor(sq, m); }
        if (s == 0) st[row] = make_float2(sm, sq);
    } else if (b < Ginit + Gwcvt) {
        int i = (b - Ginit) * 256 + tid;   // 4 types x 65536
        int t = i >> 16;
        int r = i & 65535;
        if (r < 16384) {
            int k = r >> 7, c = r & 127;
            w1t[(size_t)t * 16384 + c * 128 + k] = f2bf(pw1[(size_t)t * 16384 + k * 128 + c]);
        } else if (r < 32768) {
            int rr = r - 16384;
            int k = rr >> 7, c = rr & 127;
            w2t[(size_t)t * 16384 + c * 128 + k] = f2bf(pw2[(size_t)t * 16384 + k * 128 + c]);
        } else {
            int rr = r - 32768;
            int k = rr >> 7, c = rr & 127;
            uwt[(size_t)t * 32768 + c * 256 + k] = f2bf(uw[(size_t)t * 32768 + k * 128 + c]);
        }
    } else {
        int i = (b - Ginit - Gwcvt) * 256 + tid;
        if (i < Eab) atomicAdd(&cnt_b[dst_b[i]], 1);
        else if (i - Eab < Eba) atomicAdd(&cnt_a[dst_a[i - Eab]], 1);
    }
}

// ---------- parallel scan, phase A ----------
__global__ __launch_bounds__(256)
void k_scanA(const int* __restrict__ cnt0, int* __restrict__ rowp0, int* __restrict__ part0,
             int n0, int Gb0,
             const int* __restrict__ cnt1, int* __restrict__ rowp1, int* __restrict__ part1, int n1)
{
    const int b = blockIdx.x;
    const bool sel = b < Gb0;
    const int* cnt = sel ? cnt0 : cnt1;
    int* rowp      = sel ? rowp0 : rowp1;
    int* part      = sel ? part0 : part1;
    const int n    = sel ? n0 : n1;
    const int bb   = sel ? b : b - Gb0;

    __shared__ int wsum[4];
    const int tid = threadIdx.x, lane = tid & 63, wid = tid >> 6;
    const int i = bb * 256 + tid;
    int v = (i < n) ? cnt[i] : 0;
    int incl = v;
    #pragma unroll
    for (int d = 1; d < 64; d <<= 1) {
        int t = __shfl_up(incl, d);
        if (lane >= d) incl += t;
    }
    if (lane == 63) wsum[wid] = incl;
    __syncthreads();
    int base = 0;
    #pragma unroll
    for (int j = 0; j < 4; ++j) if (j < wid) base += wsum[j];
    int excl = base + incl - v;
    if (i < n) rowp[i] = excl;
    if (tid == 255) part[bb] = excl + v;
}

// ---------- parallel scan, phase B ----------
__global__ __launch_bounds__(256)
void k_scanB(int* __restrict__ rowp0, const int* __restrict__ part0, int* __restrict__ off0,
             int n0, int Gb0,
             int* __restrict__ rowp1, const int* __restrict__ part1, int* __restrict__ off1, int n1)
{
    const int b = blockIdx.x;
    const bool sel = b < Gb0;
    int* rowp       = sel ? rowp0 : rowp1;
    const int* part = sel ? part0 : part1;
    int* off        = sel ? off0 : off1;
    const int n     = sel ? n0 : n1;
    const int bb    = sel ? b : b - Gb0;
    const int Gl    = sel ? Gb0 : (int)gridDim.x - Gb0;

    __shared__ int base_s;
    const int tid = threadIdx.x;
    if (tid < 64) {
        int s = 0;
        for (int j = tid; j < bb; j += 64) s += part[j];
        #pragma unroll
        for (int m = 1; m < 64; m <<= 1) s += __shfl_xor(s, m);
        if (tid == 0) base_s = s;
    }
    __syncthreads();
    const int base = base_s;
    const int i = bb * 256 + tid;
    if (i < n) {
        int r = rowp[i] + base;
        rowp[i] = r;
        off[i] = r;
    }
    if (bb == Gl - 1 && tid == 0) rowp[n] = base + part[bb];
}

__global__ __launch_bounds__(256)
void k_scatter_dual(const int* __restrict__ src_b, const int* __restrict__ dst_b, int Eab,
                    int* __restrict__ off_b, int* __restrict__ srcs_ab,
                    const int* __restrict__ src_a, const int* __restrict__ dst_a, int Eba,
                    int* __restrict__ off_a, int* __restrict__ srcs_ba)
{
    int i = blockIdx.x * 256 + threadIdx.x;
    if (i < Eab) {
        int p = atomicAdd(&off_b[dst_b[i]], 1);
        srcs_ab[p] = src_b[i];
    } else if (i - Eab < Eba) {
        int j = i - Eab;
        int p = atomicAdd(&off_a[dst_a[j]], 1);
        srcs_ba[p] = src_a[j];
    }
}

// ---------- fully fused conv: 32-node tile, 8 waves; srcs slice pre-staged in LDS ----------
__device__ __forceinline__ void layer_body(
    char* smem,
    const ushort* __restrict__ xdst, const ushort* __restrict__ xsrc,
    const float2* __restrict__ stat_src,
    const int* __restrict__ rowp, const int* __restrict__ srcs,
    const ushort* __restrict__ w1t, const float* __restrict__ b1,
    const ushort* __restrict__ w2t, const float* __restrict__ b2,
    const float* __restrict__ mg, const float* __restrict__ mbt,
    const ushort* __restrict__ uwt, const float* __restrict__ ub,
    const float* __restrict__ ng, const float* __restrict__ nb,
    ushort* __restrict__ xout, float2* __restrict__ statOut, int N, int blk,
    const float* __restrict__ hw, const float* __restrict__ hb,
    float* __restrict__ hout, int headS)
{
    ushort* As = (ushort*)smem;              // 32x128 bf16, swizzled (x_dst)
    ushort* Hs = (ushort*)(smem + 8192);     // 32x128 bf16, swizzled (relu(h), then agg)
    ushort* P  = (ushort*)(smem + 16384);    // 32x128 bf16, linear (pred)
    float (*os)[CC + 4] = (float(*)[CC + 4])(smem + 8192);  // overlays Hs+P after update GEMM
    int* sL   = (int*)(smem + 25088);        // block srcs slice (ECAP ints)
    int* shrp = (int*)(smem + 25088 + ECAP * 4);  // 33-entry rowp slice

    const int tid = threadIdx.x;
    const int base = blk * 32;
    const int w = tid >> 6, l = tid & 63;
    const int lr = l & 15, lg = l >> 4;

    if (tid < 33) {
        int nn = base + tid;
        shrp[tid] = rowp[nn < N ? nn : N];
    }
    {   // stage x_dst -> As (swizzled): one bf16x8 per thread
        int row = tid >> 4, k0 = (tid & 15) << 3;
        int node = base + row;
        bf16x8 v0 = {};
        if (node < N)
            v0 = *reinterpret_cast<const bf16x8*>(xdst + (size_t)node * CC + k0);
        *reinterpret_cast<bf16x8*>(&As[swz128(row, k0)]) = v0;
    }
    // stage the block's srcs slice (wave-uniform bounds; one int per thread)
    const int jb0 = rowp[base];
    {
        int top = base + 32; if (top > N) top = N;
        const int je0 = rowp[top];
        int ec = je0 - jb0; if (ec > ECAP) ec = ECAP;
        if (tid < ec) sL[tid] = srcs[jb0 + tid];
    }
    __syncthreads();

    // pred GEMM1: Hs = relu(As @ w1 + b1); wave w owns cols [w*16, w*16+16)
    {
        f32x4 acc[2] = {};
        for (int kb = 0; kb < 4; ++kb) {
            int k = kb * 32 + lg * 8;
            bf16x8 a0 = *reinterpret_cast<const bf16x8*>(&As[swz128(lr, k)]);
            bf16x8 a1 = *reinterpret_cast<const bf16x8*>(&As[swz128(lr + 16, k)]);
            bf16x8 b0 = *reinterpret_cast<const bf16x8*>(&w1t[(size_t)(w * 16 + lr) * 128 + k]);
            acc[0] = MFMA16(a0, b0, acc[0]);
            acc[1] = MFMA16(a1, b0, acc[1]);
        }
        float bc = b1[w * 16 + lr];
        int col = w * 16 + lr;
        #pragma unroll
        for (int mi = 0; mi < 2; ++mi)
            #pragma unroll
            for (int j = 0; j < 4; ++j) {
                int row = mi * 16 + lg * 4 + j;
                Hs[swz128(row, col)] = f2bf(fmaxf(acc[mi][j] + bc, 0.f));
            }
    }
    __syncthreads();

    // pred GEMM2: P = Hs @ w2 + b2  (linear layout)
    {
        f32x4 acc[2] = {};
        for (int kb = 0; kb < 4; ++kb) {
            int k = kb * 32 + lg * 8;
            bf16x8 a0 = *reinterpret_cast<const bf16x8*>(&Hs[swz128(lr, k)]);
            bf16x8 a1 = *reinterpret_cast<const bf16x8*>(&Hs[swz128(lr + 16, k)]);
            bf16x8 b0 = *reinterpret_cast<const bf16x8*>(&w2t[(size_t)(w * 16 + lr) * 128 + k]);
            acc[0] = MFMA16(a0, b0, acc[0]);
            acc[1] = MFMA16(a1, b0, acc[1]);
        }
        float bc = b2[w * 16 + lr];
        int col = w * 16 + lr;
        #pragma unroll
        for (int mi = 0; mi < 2; ++mi)
            #pragma unroll
            for (int j = 0; j < 4; ++j) {
                int row = mi * 16 + lg * 4 + j;
                P[row * CC + col] = f2bf(acc[mi][j] + bc);
            }
    }
    __syncthreads();

    // agg phase: wave w owns nodes w*4..w*4+3; quarter-wave = 4 edges in flight (round-6 math)
    {
        const int quarter = l >> 4;
        const int c = (l & 15) * 8;
        const float4 g0 = *reinterpret_cast<const float4*>(mg + c);
        const float4 g1 = *reinterpret_cast<const float4*>(mg + c + 4);
        const float4 e0 = *reinterpret_cast<const float4*>(mbt + c);
        const float4 e1 = *reinterpret_cast<const float4*>(mbt + c + 4);
        const float gv[8] = { g0.x, g0.y, g0.z, g0.w, g1.x, g1.y, g1.z, g1.w };
        const float bv[8] = { e0.x, e0.y, e0.z, e0.w, e1.x, e1.y, e1.z, e1.w };
        for (int i = 0; i < 4; ++i) {
            const int nl_ = w * 4 + i;
            const int d = base + nl_;
            if (d >= N) break;
            bf16x8 prb = *reinterpret_cast<const bf16x8*>(&P[nl_ * CC + c]);
            float pr[8];
            #pragma unroll
            for (int q = 0; q < 8; ++q) pr[q] = bf2f((ushort)prb[q]);
            float sp = 0.f, qp = 0.f;
            #pragma unroll
            for (int q = 0; q < 8; ++q) { sp += pr[q]; qp = fmaf(pr[q], pr[q], qp); }
            #pragma unroll
            for (int m = 1; m < 16; m <<= 1) { sp += __shfl_xor(sp, m); qp += __shfl_xor(qp, m); }
            const int jb = shrp[nl_], je = shrp[nl_ + 1];
            const int deg = je - jb;
            float a[8] = {};
            float rsum = 0.f, cmsum = 0.f;
            for (int j = jb + quarter; j < je; j += 4) {
                const int le = j - jb0;
                const int sidx = (le < ECAP) ? sL[le] : srcs[j];
                bf16x8 xb_ = *reinterpret_cast<const bf16x8*>(xsrc + (size_t)sidx * CC + c);
                const float2 st = stat_src[sidx];
                float xj[8];
                #pragma unroll
                for (int q = 0; q < 8; ++q) xj[q] = bf2f((ushort)xb_[q]);
                float dA = 0.f, dB = 0.f;
                #pragma unroll
                for (int q = 0; q < 4; ++q) dA = fmaf(xj[q], pr[q], dA);
                #pragma unroll
                for (int q = 4; q < 8; ++q) dB = fmaf(xj[q], pr[q], dB);
                float dot = dA + dB;
                #pragma unroll
                for (int m = 1; m < 16; m <<= 1) dot += __shfl_xor(dot, m);
                const float mean = (st.x - sp) * (1.f / 128.f);
                const float var = fmaf(-2.f, dot, st.y + qp) * (1.f / 128.f) - mean * mean;
                const float r = rsqrtf(var + 1e-5f);
                rsum += r;
                cmsum = fmaf(mean, r, cmsum);
                #pragma unroll
                for (int q = 0; q < 8; ++q) a[q] = fmaf(xj[q], r, a[q]);
            }
            #pragma unroll
            for (int q = 0; q < 8; ++q) { a[q] += __shfl_xor(a[q], 16); a[q] += __shfl_xor(a[q], 32); }
            rsum += __shfl_xor(rsum, 16);  rsum += __shfl_xor(rsum, 32);
            cmsum += __shfl_xor(cmsum, 16); cmsum += __shfl_xor(cmsum, 32);
            if (quarter == 0) {
                ushort o8[8];
                if (deg > 0) {
                    const float inv = 1.f / (float)deg;
                    #pragma unroll
                    for (int q = 0; q < 8; ++q)
                        o8[q] = f2bf(fmaf((a[q] - pr[q] * rsum - cmsum) * inv, gv[q], bv[q]));
                } else {
                    #pragma unroll
                    for (int q = 0; q < 8; ++q) o8[q] = 0;
                }
                *reinterpret_cast<bf16x8*>(&Hs[swz128(nl_, c)]) = *reinterpret_cast<bf16x8*>(&o8[0]);
            }
        }
    }
    __syncthreads();

    // update GEMM: concat(x=As | agg=Hs) @ uwt + ub, K=256; wave w owns 16 cols
    f32x4 acc[2] = {};
    for (int kb = 0; kb < 8; ++kb) {
        int k = kb * 32 + lg * 8;
        const ushort* Ab = (k < 128) ? As : Hs;
        int kl = k & 127;
        bf16x8 a0 = *reinterpret_cast<const bf16x8*>(&Ab[swz128(lr, kl)]);
        bf16x8 a1 = *reinterpret_cast<const bf16x8*>(&Ab[swz128(lr + 16, kl)]);
        bf16x8 b0 = *reinterpret_cast<const bf16x8*>(&uwt[(size_t)(w * 16 + lr) * 256 + k]);
        acc[0] = MFMA16(a0, b0, acc[0]);
        acc[1] = MFMA16(a1, b0, acc[1]);
    }
    __syncthreads();   // all reads of As/Hs done before os overlays them

    {
        float bc = ub[w * 16 + lr];
        int col = w * 16 + lr;
        #pragma unroll
        for (int mi = 0; mi < 2; ++mi)
            #pragma unroll
            for (int j = 0; j < 4; ++j) {
                int row = mi * 16 + lg * 4 + j;
                os[row][col] = fmaxf(acc[mi][j] + bc, 0.f);
            }
    }
    __syncthreads();

    // node LayerNorm + relu + stats (+head); 16 lanes/node, 8 channels/lane
    const int nl = tid >> 4;
    const int cl = tid & 15;
    float vals[8];
    float sm = 0.f, sq = 0.f;
    #pragma unroll
    for (int t = 0; t < 8; ++t) {
        float u = os[nl][cl + 16 * t];
        vals[t] = u; sm += u; sq = fmaf(u, u, sq);
    }
    #pragma unroll
    for (int m = 1; m < 16; m <<= 1) { sm += __shfl_xor(sm, m); sq += __shfl_xor(sq, m); }
    float mean = sm * (1.f / 128.f);
    float var = sq * (1.f / 128.f) - mean * mean;
    float r = rsqrtf(var + 1e-5f);
    int node = base + nl;
    if (node < N) {
        float so = 0.f, sqo = 0.f, hsum = 0.f;
        bool doHead = (node < headS);
        #pragma unroll
        for (int t = 0; t < 8; ++t) {
            int cch = cl + 16 * t;
            float o = fmaxf(fmaf((vals[t] - mean) * r, ng[cch], nb[cch]), 0.f);
            ushort ob = f2bf(o);
            xout[(size_t)node * CC + cch] = ob;
            float orr = bf2f(ob);
            so += orr; sqo = fmaf(orr, orr, sqo);
            if (doHead) hsum = fmaf(o, hw[cch], hsum);
        }
        #pragma unroll
        for (int m = 1; m < 16; m <<= 1) { so += __shfl_xor(so, m); sqo += __shfl_xor(sqo, m); }
        if (doHead) {
            #pragma unroll
            for (int m = 1; m < 16; m <<= 1) hsum += __shfl_xor(hsum, m);
            if (cl == 0) hout[node] = hsum + hb[0];
        }
        if (cl == 0) statOut[node] = make_float2(so, sqo);
    }
}

__global__ __launch_bounds__(512)
void k_layer_dual(
    const ushort* __restrict__ xb_c, const ushort* __restrict__ xa_c,
    const float2* __restrict__ stat_a_c, const float2* __restrict__ stat_b_c,
    const int* __restrict__ rowp_b, const int* __restrict__ srcs_ab,
    const int* __restrict__ rowp_a, const int* __restrict__ srcs_ba,
    ushort* __restrict__ xb_n, ushort* __restrict__ xa_n,
    float2* __restrict__ stat_b_n, float2* __restrict__ stat_a_n,
    int NB, int NA, int GB,
    const ushort* __restrict__ w1t0, const float* __restrict__ b10,
    const ushort* __restrict__ w2t0, const float* __restrict__ b20,
    const float* __restrict__ mg0, const float* __restrict__ mb0,
    const ushort* __restrict__ uwt0, const float* __restrict__ ub0,
    const float* __restrict__ ng0, const float* __restrict__ nb0,
    const ushort* __restrict__ w1t1, const float* __restrict__ b11,
    const ushort* __restrict__ w2t1, const float* __restrict__ b21,
    const float* __restrict__ mg1, const float* __restrict__ mb1,
    const ushort* __restrict__ uwt1, const float* __restrict__ ub1,
    const float* __restrict__ ng1, const float* __restrict__ nb1,
    const float* __restrict__ hw, const float* __restrict__ hb,
    float* __restrict__ hout, int headS)
{
    __shared__ __align__(16) char smem[25088 + ECAP * 4 + 144];
    if ((int)blockIdx.x < GB)
        layer_body(smem, xb_c, xa_c, stat_a_c, rowp_b, srcs_ab,
                   w1t0, b10, w2t0, b20, mg0, mb0, uwt0, ub0, ng0, nb0,
                   xb_n, stat_b_n, NB, blockIdx.x, hw, hb, hout, 0);
    else
        layer_body(smem, xa_c, xb_c, stat_b_c, rowp_a, srcs_ba,
                   w1t1, b11, w2t1, b21, mg1, mb1, uwt1, ub1, ng1, nb1,
                   xa_n, stat_a_n, NA, blockIdx.x - GB, hw, hb, hout, headS);
}

extern "C" void kernel_launch(void* const* d_in, const int* in_sizes, int n_in,
                              void* d_out, int out_size, void* d_ws, size_t ws_size,
                              hipStream_t stream)
{
    const float* x_a_in = (const float*)d_in[0];
    const float* x_b_in = (const float*)d_in[1];
    const int*   e_ab   = (const int*)d_in[2];
    const int*   e_ba   = (const int*)d_in[3];
    const float* pw1    = (const float*)d_in[4];
    const float* pb1    = (const float*)d_in[5];
    const float* pw2    = (const float*)d_in[6];
    const float* pb2    = (const float*)d_in[7];
    const float* mgam   = (const float*)d_in[8];
    const float* mbet   = (const float*)d_in[9];
    const float* uw     = (const float*)d_in[10];
    const float* ubias  = (const float*)d_in[11];
    const float* ngam   = (const float*)d_in[12];
    const float* nbet   = (const float*)d_in[13];
    const float* hw     = (const float*)d_in[14];
    const float* hb     = (const float*)d_in[15];

    const int NA  = in_sizes[0] / CC;
    const int NB  = in_sizes[1] / CC;
    const int Eab = in_sizes[2] / 2;
    const int Eba = in_sizes[3] / 2;

    float* ws = (float*)d_ws;
    size_t off = 0;  // in floats
    ushort* xa0 = (ushort*)(ws + off); off += (size_t)NA * CC / 2;
    ushort* xa1 = (ushort*)(ws + off); off += (size_t)NA * CC / 2;
    ushort* xb0 = (ushort*)(ws + off); off += (size_t)NB * CC / 2;
    ushort* xb1 = (ushort*)(ws + off); off += (size_t)NB * CC / 2;
    float2* sa0 = (float2*)(ws + off); off += (size_t)NA * 2;
    float2* sa1 = (float2*)(ws + off); off += (size_t)NA * 2;
    float2* sb0 = (float2*)(ws + off); off += (size_t)NB * 2;
    float2* sb1 = (float2*)(ws + off); off += (size_t)NB * 2;
    ushort* w1t = (ushort*)(ws + off); off += 4 * 16384 / 2;
    ushort* w2t = (ushort*)(ws + off); off += 4 * 16384 / 2;
    ushort* uwt = (ushort*)(ws + off); off += 4 * 32768 / 2;
    int* iw = (int*)(ws + off);
    size_t ioff = 0;
    int* cnt_b   = iw + ioff; ioff += NB;
    int* cnt_a   = iw + ioff; ioff += NA;
    int* rowp_b  = iw + ioff; ioff += NB + 1;
    int* rowp_a  = iw + ioff; ioff += NA + 1;
    int* off_b   = iw + ioff; ioff += NB;
    int* off_a   = iw + ioff; ioff += NA;
    int* srcs_ab = iw + ioff; ioff += Eab;
    int* srcs_ba = iw + ioff; ioff += Eba;
    const int GbS = (NB + 255) / 256, GaS = (NA + 255) / 256;
    int* part_b  = iw + ioff; ioff += GbS;
    int* part_a  = iw + ioff; ioff += GaS;

    const int GB = (NB + 31) / 32, GA = (NA + 31) / 32;
    const int Ginit = (NA + NB + 7) / 8;
    const int Gwcvt = 1024;
    const int Ghist = (Eab + Eba + 255) / 256;

    hipMemsetAsync(cnt_b, 0, (size_t)(NB + NA) * sizeof(int), stream);
    k_setup<<<dim3(Ginit + Gwcvt + Ghist), dim3(256), 0, stream>>>(
        x_a_in, xa0, sa0, NA, x_b_in, xb0, sb0, NB,
        pw1, pw2, uw, w1t, w2t, uwt,
        e_ab + Eab, Eab, cnt_b, e_ba + Eba, Eba, cnt_a,
        Ginit, Gwcvt);
    k_scanA<<<dim3(GbS + GaS), dim3(256), 0, stream>>>(
        cnt_b, rowp_b, part_b, NB, GbS, cnt_a, rowp_a, part_a, NA);
    k_scanB<<<dim3(GbS + GaS), dim3(256), 0, stream>>>(
        rowp_b, part_b, off_b, NB, GbS, rowp_a, part_a, off_a, NA);
    k_scatter_dual<<<dim3((Eab + Eba + 255) / 256), dim3(256), 0, stream>>>(
        e_ab, e_ab + Eab, Eab, off_b, srcs_ab,
        e_ba, e_ba + Eba, Eba, off_a, srcs_ba);

    ushort* xac = xa0; ushort* xan = xa1;
    ushort* xbc = xb0; ushort* xbn = xb1;
    float2* sac = sa0; float2* san = sa1;
    float2* sbc = sb0; float2* sbn = sb1;

    for (int lyr = 0; lyr < 2; ++lyr) {
        int t0 = lyr * 2 + 0;   // conv a->b (dst = b)
        int t1 = lyr * 2 + 1;   // conv b->a (dst = a)
        int headS = (lyr == 1) ? out_size : 0;

        k_layer_dual<<<dim3(GB + GA), dim3(512), 0, stream>>>(
            xbc, xac, sac, sbc,
            rowp_b, srcs_ab, rowp_a, srcs_ba,
            xbn, xan, sbn, san,
            NB, NA, GB,
            w1t + (size_t)t0 * 16384, pb1 + t0 * CC, w2t + (size_t)t0 * 16384, pb2 + t0 * CC,
            mgam + t0 * CC, mbet + t0 * CC,
            uwt + (size_t)t0 * 32768, ubias + t0 * CC, ngam + t0 * CC, nbet + t0 * CC,
            w1t + (size_t)t1 * 16384, pb1 + t1 * CC, w2t + (size_t)t1 * 16384, pb2 + t1 * CC,
            mgam + t1 * CC, mbet + t1 * CC,
            uwt + (size_t)t1 * 32768, ubias + t1 * CC, ngam + t1 * CC, nbet + t1 * CC,
            hw, hb, (float*)d_out, headS);

        ushort* t;
        t = xac; xac = xan; xan = t;
        t = xbc; xbc = xbn; xbn = t;
        float2* s;
        s = sac; sac = san; san = s;
        s = sbc; sbc = sbn; sbn = s;
    }
}